// Round 10
// baseline (1129.740 us; speedup 1.0000x reference)
//
#include <hip/hip_runtime.h>
#include <hip/hip_bf16.h>
#include <hip/hip_fp8.h>

#define N_NODES 100000
#define N_EDGES 1600000
#define N_GRAPHS 2000
#define D_IN 600
#define D_H 300
#define D_OUT 2

#define NPAD 320        // padded hidden width
#define K1PAD 640
#define K2PAD 320
#define MPAD 100096     // 782 * 128
#define PLANE 4000000   // bytes per column-group plane: 100000 nodes * 40 B

typedef __bf16 bf16;
typedef __bf16 bf16x4 __attribute__((ext_vector_type(4)));
typedef __bf16 bf16x8 __attribute__((ext_vector_type(8)));
typedef float f32x4 __attribute__((ext_vector_type(4)));
typedef float f32x2 __attribute__((ext_vector_type(2)));

__device__ __forceinline__ unsigned char ff8(float f) {
    __hip_fp8_e4m3 t(f); return (unsigned char)t.__x;
}

// ---------------- degree counting ----------------
__global__ __launch_bounds__(256) void count_deg(const int* __restrict__ src,
                                                 const int* __restrict__ dst,
                                                 int* __restrict__ deg_out,
                                                 int* __restrict__ deg_in) {
    int e = blockIdx.x * blockDim.x + threadIdx.x;
    if (e < N_EDGES) {
        atomicAdd(&deg_out[src[e]], 1);
        atomicAdd(&deg_in[dst[e]], 1);
    }
}

// ---------------- per-block sums of deg_in ----------------
__global__ __launch_bounds__(256) void block_sum(const int* __restrict__ deg_in,
                                                 int* __restrict__ bsum) {
    __shared__ int s[256];
    int i = blockIdx.x * 256 + threadIdx.x;
    s[threadIdx.x] = (i < N_NODES) ? deg_in[i] : 0;
    __syncthreads();
    for (int off = 128; off; off >>= 1) {
        if (threadIdx.x < off) s[threadIdx.x] += s[threadIdx.x + off];
        __syncthreads();
    }
    if (threadIdx.x == 0) bsum[blockIdx.x] = s[0];
}

// ---------------- serial scan over block sums ----------------
__global__ void scan_serial(const int* __restrict__ bsum, int* __restrict__ boff, int nb) {
    if (threadIdx.x == 0 && blockIdx.x == 0) {
        int run = 0;
        for (int i = 0; i < nb; ++i) { boff[i] = run; run += bsum[i]; }
    }
}

// ---------------- per-node CSR offsets + inv-sqrt degrees ----------------
__global__ __launch_bounds__(256) void node_offsets(const int* __restrict__ deg_in,
                                                    const int* __restrict__ deg_out,
                                                    const int* __restrict__ boff,
                                                    int* __restrict__ row_start,
                                                    int* __restrict__ cursor,
                                                    float* __restrict__ inv_in,
                                                    float* __restrict__ inv_out) {
    __shared__ int s[256];
    int i = blockIdx.x * 256 + threadIdx.x;
    int d = (i < N_NODES) ? deg_in[i] : 0;
    s[threadIdx.x] = d;
    __syncthreads();
    for (int off = 1; off < 256; off <<= 1) {
        int v = 0;
        if (threadIdx.x >= off) v = s[threadIdx.x - off];
        __syncthreads();
        if (threadIdx.x >= off) s[threadIdx.x] += v;
        __syncthreads();
    }
    if (i < N_NODES) {
        int excl = s[threadIdx.x] - d;
        int rs = boff[blockIdx.x] + excl;
        row_start[i] = rs;
        cursor[i] = rs;
        int di = deg_in[i];
        int dout = deg_out[i];
        inv_in[i]  = (di   > 0) ? rsqrtf((float)di)   : 0.0f;
        inv_out[i] = (dout > 0) ? rsqrtf((float)dout) : 0.0f;
    }
}

// ---------------- fill CSR adjacency ----------------
__global__ __launch_bounds__(256) void fill_csr(const int* __restrict__ src,
                                                const int* __restrict__ dst,
                                                int* __restrict__ cursor,
                                                int* __restrict__ adj) {
    int e = blockIdx.x * blockDim.x + threadIdx.x;
    if (e < N_EDGES) {
        int pos = atomicAdd(&cursor[dst[e]], 1);
        adj[pos] = src[e];
    }
}

// ---------------- W [K][N] fp32 -> Bt [NPAD][Kpad] bf16 ----------------
__global__ __launch_bounds__(256) void conv_bt(const float* __restrict__ W, bf16* __restrict__ Bt,
                                               int K, int N, int Kpad) {
    int idx = blockIdx.x * 256 + threadIdx.x;
    int k = idx % Kpad;
    int n = idx / Kpad;
    if (n >= NPAD) return;
    bf16 v = (bf16)0.0f;
    if (k < K && n < N) v = (bf16)W[(size_t)k * N + n];
    Bt[(size_t)n * Kpad + k] = v;
}

// ---------------- pad bias / Wfc ----------------
__global__ __launch_bounds__(256) void prep_small(const float* __restrict__ b1,
                                                  const float* __restrict__ b2,
                                                  const float* __restrict__ Wfc,
                                                  float* __restrict__ b1p,
                                                  float* __restrict__ b2p,
                                                  float* __restrict__ wfcp) {
    int i = blockIdx.x * 256 + threadIdx.x;
    if (i < NPAD) {
        b1p[i] = (i < D_H) ? b1[i] : 0.f;
        b2p[i] = (i < D_H) ? b2[i] : 0.f;
    }
    if (i < NPAD * 2) {
        wfcp[i] = (i < D_H * 2) ? Wfc[i] : 0.f;
    }
}

// ---------------- reg-staged MFMA GEMM, fp8 PLANAR output ----------------
template<int NK, bool AF32>
__global__ __launch_bounds__(512) void gemm_rs(const float* __restrict__ Af,
                                               const bf16* __restrict__ Ab,
                                               const bf16* __restrict__ Bt,
                                               const float* __restrict__ rowscale,
                                               unsigned char* __restrict__ C8,
                                               int M) {
    __shared__ bf16 As[128 * 64];
    __shared__ bf16 Bs[320 * 64];
    const int tid = threadIdx.x;
    const int lane = tid & 63;
    const int wid = tid >> 6;
    const int wr = wid >> 2;
    const int wc = wid & 3;
    const int blockRow = blockIdx.x * 128;
    const int Kpad = NK * 64;
    const size_t rowBytes = (size_t)Kpad * 2;

    f32x4 acc[4][5] = {};

    int aO[2], aRow[2], aKs[2];
    #pragma unroll
    for (int c = 0; c < 2; ++c) {
        int o = c * 8192 + tid * 16;
        int row = o >> 7;
        int slot = (o >> 4) & 7;
        aO[c] = o; aRow[c] = row; aKs[c] = (slot ^ (row & 7)) * 8;
    }
    int bO[5], bRow[5], bKs[5];
    #pragma unroll
    for (int c = 0; c < 5; ++c) {
        int o = c * 8192 + tid * 16;
        int row = o >> 7;
        int slot = (o >> 4) & 7;
        bO[c] = o; bRow[c] = row; bKs[c] = (slot ^ (row & 7)) * 8;
    }

    float4 fA[2][2];
    bf16x8 sA[2];
    bf16x8 sB[5];

    auto loadTile = [&](int t) {
        #pragma unroll
        for (int c = 0; c < 2; ++c) {
            if (AF32) {
                int gr = blockRow + aRow[c];
                int k = t * 64 + aKs[c];
                if (gr < N_NODES && k < D_IN) {
                    const float* p = Af + (size_t)gr * D_IN + k;
                    fA[c][0] = *(const float4*)p;
                    fA[c][1] = *(const float4*)(p + 4);
                } else {
                    fA[c][0] = make_float4(0.f, 0.f, 0.f, 0.f);
                    fA[c][1] = make_float4(0.f, 0.f, 0.f, 0.f);
                }
            } else {
                const char* g = (const char*)Ab + (size_t)(blockRow + aRow[c]) * rowBytes
                                + (size_t)t * 128 + aKs[c] * 2;
                sA[c] = *(const bf16x8*)g;
            }
        }
        #pragma unroll
        for (int c = 0; c < 5; ++c) {
            const char* g = (const char*)Bt + (size_t)bRow[c] * rowBytes
                            + (size_t)t * 128 + bKs[c] * 2;
            sB[c] = *(const bf16x8*)g;
        }
    };

    loadTile(0);

    for (int t = 0; t < NK; ++t) {
        __syncthreads();
        #pragma unroll
        for (int c = 0; c < 2; ++c) {
            bf16x8 v;
            if (AF32) {
                v[0] = (bf16)fA[c][0].x; v[1] = (bf16)fA[c][0].y;
                v[2] = (bf16)fA[c][0].z; v[3] = (bf16)fA[c][0].w;
                v[4] = (bf16)fA[c][1].x; v[5] = (bf16)fA[c][1].y;
                v[6] = (bf16)fA[c][1].z; v[7] = (bf16)fA[c][1].w;
            } else {
                v = sA[c];
            }
            *(bf16x8*)((char*)As + aO[c]) = v;
        }
        #pragma unroll
        for (int c = 0; c < 5; ++c)
            *(bf16x8*)((char*)Bs + bO[c]) = sB[c];
        __syncthreads();
        if (t + 1 < NK) loadTile(t + 1);
        #pragma unroll
        for (int kk = 0; kk < 2; ++kk) {
            int slot = kk * 4 + (lane >> 4);
            bf16x8 af[4], bfr[5];
            #pragma unroll
            for (int mi = 0; mi < 4; ++mi) {
                int row = wr * 64 + mi * 16 + (lane & 15);
                int addr = row * 128 + ((slot ^ (row & 7)) << 4);
                af[mi] = *(const bf16x8*)((const char*)As + addr);
            }
            #pragma unroll
            for (int ni = 0; ni < 5; ++ni) {
                int row = wc * 80 + ni * 16 + (lane & 15);
                int addr = row * 128 + ((slot ^ (row & 7)) << 4);
                bfr[ni] = *(const bf16x8*)((const char*)Bs + addr);
            }
            #pragma unroll
            for (int mi = 0; mi < 4; ++mi)
                #pragma unroll
                for (int ni = 0; ni < 5; ++ni)
                    acc[mi][ni] = __builtin_amdgcn_mfma_f32_16x16x32_bf16(af[mi], bfr[ni], acc[mi][ni], 0, 0, 0);
        }
    }
    // epilogue: planar fp8 write  (plane g = cols [40g, 40g+40))
    #pragma unroll
    for (int mi = 0; mi < 4; ++mi) {
        #pragma unroll
        for (int i = 0; i < 4; ++i) {
            int gr = blockRow + wr * 64 + mi * 16 + ((lane >> 4) << 2) + i;
            if (gr >= M) continue;
            float sc = rowscale[gr];
            #pragma unroll
            for (int ni = 0; ni < 5; ++ni) {
                int gc = wc * 80 + ni * 16 + (lane & 15);
                int g = gc / 40;
                int o = gc - g * 40;
                C8[(size_t)g * PLANE + (size_t)gr * 40 + o] = ff8(acc[mi][ni][i] * sc);
            }
        }
    }
}

// ---------------- XCD-sharded aggregation ----------------
// group g = blockIdx&7 (round-robin -> one XCD per group); plane g (3.81 MiB) fits that
// XCD's L2. Wave-per-node: lane = eslot*10 + di; one dword load covers 6 edges x 40 B.
template<bool FUSE_FC>
__global__ __launch_bounds__(256) void agg_shard(const unsigned char* __restrict__ m8,
                                                 const int* __restrict__ row_start,
                                                 const int* __restrict__ deg_in,
                                                 const int* __restrict__ adj,
                                                 const float* __restrict__ inv_in,
                                                 const float* __restrict__ biasp,
                                                 const float* __restrict__ wfcp,
                                                 bf16* __restrict__ h,
                                                 float2* __restrict__ zpart) {
    __shared__ f32x4 red[256];
    const int lane = threadIdx.x & 63;
    const int wid = threadIdx.x >> 6;
    const int g = blockIdx.x & 7;
    const int node = (blockIdx.x >> 3) * 4 + wid;   // grid sized so node < N_NODES
    const int s = __builtin_nontemporal_load(row_start + node);
    const int d = __builtin_nontemporal_load(deg_in + node);
    const int eslot = lane / 10;      // 0..6 (lanes 60..63 -> 6, inactive)
    const int di = lane - eslot * 10; // 0..9
    const bool active = lane < 60;
    const unsigned char* plane = m8 + (size_t)g * PLANE;
    const int di4 = di * 4;

    // preload first 64 adjacency entries into registers (bpermute source)
    int adjv = (lane < d) ? __builtin_nontemporal_load(adj + s + lane) : 0;

    f32x4 acc = {0.f, 0.f, 0.f, 0.f};
    for (int e = 0; e < d; e += 18) {
        unsigned int u[3] = {0u, 0u, 0u};
        #pragma unroll
        for (int q = 0; q < 3; ++q) {
            int ee = e + q * 6 + eslot;
            bool v = active && (ee < d);
            int idx = __builtin_amdgcn_ds_bpermute(ee << 2, adjv);
            if (ee >= 64 && v) idx = __builtin_nontemporal_load(adj + s + ee);
            if (v) u[q] = *(const unsigned int*)(plane + (size_t)idx * 40 + di4);
        }
        #pragma unroll
        for (int q = 0; q < 3; ++q) {
            f32x2 lo = __builtin_amdgcn_cvt_pk_f32_fp8(u[q], false);
            f32x2 hi = __builtin_amdgcn_cvt_pk_f32_fp8(u[q], true);
            acc[0] += lo[0]; acc[1] += lo[1]; acc[2] += hi[0]; acc[3] += hi[1];
        }
    }
    red[threadIdx.x] = acc;
    __syncthreads();
    if (lane < 10) {
        f32x4 a = red[wid * 64 + lane];
        #pragma unroll
        for (int k = 1; k < 6; ++k) {
            f32x4 b = red[wid * 64 + k * 10 + lane];
            a[0] += b[0]; a[1] += b[1]; a[2] += b[2]; a[3] += b[3];
        }
        float sc = __builtin_nontemporal_load(inv_in + node);
        int c = g * 40 + lane * 4;
        float4 bq = *(const float4*)(biasp + c);
        float h0 = fmaxf(a[0] * sc + bq.x, 0.f);
        float h1 = fmaxf(a[1] * sc + bq.y, 0.f);
        float h2 = fmaxf(a[2] * sc + bq.z, 0.f);
        float h3 = fmaxf(a[3] * sc + bq.w, 0.f);
        if (!FUSE_FC) {
            bf16x4 o;
            o[0] = (bf16)h0; o[1] = (bf16)h1; o[2] = (bf16)h2; o[3] = (bf16)h3;
            unsigned long long bits;
            __builtin_memcpy(&bits, &o, 8);
            __builtin_nontemporal_store(bits, (unsigned long long*)(h + (size_t)node * NPAD + c));
        } else {
            float4 w0 = *(const float4*)(wfcp + c * 2);
            float4 w1 = *(const float4*)(wfcp + c * 2 + 4);
            float z0 = h0 * w0.x + h1 * w0.z + h2 * w1.x + h3 * w1.z;
            float z1 = h0 * w0.y + h1 * w0.w + h2 * w1.y + h3 * w1.w;
            red[wid * 64 + lane] = f32x4{z0, z1, 0.f, 0.f};
        }
    }
    if (FUSE_FC) {
        __syncthreads();
        if (lane == 0) {
            float z0 = 0.f, z1 = 0.f;
            #pragma unroll
            for (int k = 0; k < 10; ++k) {
                f32x4 v = red[wid * 64 + k];
                z0 += v[0]; z1 += v[1];
            }
            f32x2 zp = {z0, z1};
            unsigned long long bits;
            __builtin_memcpy(&bits, &zp, 8);
            __builtin_nontemporal_store(bits, (unsigned long long*)(zpart + (size_t)node * 8 + g));
        }
    }
}

// ---------------- final: sum group z-partials, softmax, pool ----------------
__global__ __launch_bounds__(256) void pool_final(const float4* __restrict__ zp4,
                                                  const float* __restrict__ bfc,
                                                  const int* __restrict__ gid,
                                                  float* __restrict__ pooled,
                                                  int* __restrict__ gcount) {
    int n = blockIdx.x * 256 + threadIdx.x;
    if (n >= N_NODES) return;
    const float4* p = zp4 + (size_t)n * 4;
    float4 a = p[0], b = p[1], c = p[2], d = p[3];
    float z0 = (a.x + a.z) + (b.x + b.z) + (c.x + c.z) + (d.x + d.z) + bfc[0];
    float z1 = (a.y + a.w) + (b.y + b.w) + (c.y + c.w) + (d.y + d.w) + bfc[1];
    float mx = fmaxf(z0, z1);
    float e0 = __expf(z0 - mx), e1 = __expf(z1 - mx);
    float inv = 1.f / (e0 + e1);
    int g = gid[n];
    atomicAdd(&pooled[g * 2 + 0], e0 * inv);
    atomicAdd(&pooled[g * 2 + 1], e1 * inv);
    atomicAdd(&gcount[g], 1);
}

// ---------------- finalize: divide by counts ----------------
__global__ __launch_bounds__(256) void finalize(const float* __restrict__ pooled,
                                                const int* __restrict__ gcount,
                                                float* __restrict__ out) {
    int i = blockIdx.x * blockDim.x + threadIdx.x;
    if (i < N_GRAPHS * 2) {
        int g = i >> 1;
        float c = (float)max(gcount[g], 1);
        out[i] = pooled[i] / c;
    }
}

extern "C" void kernel_launch(void* const* d_in, const int* in_sizes, int n_in,
                              void* d_out, int out_size, void* d_ws, size_t ws_size,
                              hipStream_t stream) {
    const float* x   = (const float*)d_in[0];
    const float* W1  = (const float*)d_in[1];
    const float* b1  = (const float*)d_in[2];
    const float* W2  = (const float*)d_in[3];
    const float* b2  = (const float*)d_in[4];
    const float* Wfc = (const float*)d_in[5];
    const float* bfc = (const float*)d_in[6];
    const int* src   = (const int*)d_in[7];
    const int* dst   = (const int*)d_in[8];
    const int* gid   = (const int*)d_in[9];

    char* ws = (char*)d_ws;
    size_t off = 0;
    auto alloc = [&](size_t bytes) -> void* {
        void* p = ws + off;
        off = (off + bytes + 255) & ~(size_t)255;
        return p;
    };
    bf16* h_bf            = (bf16*)alloc((size_t)MPAD * NPAD * 2);         // 64.1 MB
    unsigned char* m8     = (unsigned char*)alloc((size_t)8 * PLANE);      // 32 MB planar
    float2* zpart         = (float2*)alloc((size_t)N_NODES * 8 * 8);       // 6.4 MB
    bf16* B1t    = (bf16*)alloc((size_t)NPAD * K1PAD * 2);
    bf16* B2t    = (bf16*)alloc((size_t)NPAD * K2PAD * 2);
    int*   adj      = (int*)alloc((size_t)N_EDGES * 4);
    int*   row_st   = (int*)alloc((size_t)N_NODES * 4);
    int*   cursor   = (int*)alloc((size_t)N_NODES * 4);
    int*   deg_in   = (int*)alloc((size_t)N_NODES * 4);
    int*   deg_out  = (int*)alloc((size_t)N_NODES * 4);
    float* inv_in   = (float*)alloc((size_t)N_NODES * 4);
    float* inv_out  = (float*)alloc((size_t)N_NODES * 4);
    const int NB = (N_NODES + 255) / 256;
    int*   bsum     = (int*)alloc((size_t)NB * 4);
    int*   boff     = (int*)alloc((size_t)NB * 4);
    float* pooled   = (float*)alloc((size_t)N_GRAPHS * 2 * 4);
    int*   gcount   = (int*)alloc((size_t)N_GRAPHS * 4);
    float* b1p      = (float*)alloc((size_t)NPAD * 4);
    float* b2p      = (float*)alloc((size_t)NPAD * 4);
    float* wfcp     = (float*)alloc((size_t)NPAD * 2 * 4);

    hipMemsetAsync(deg_in, 0, (size_t)N_NODES * 4, stream);
    hipMemsetAsync(deg_out, 0, (size_t)N_NODES * 4, stream);
    hipMemsetAsync(pooled, 0, (size_t)N_GRAPHS * 2 * 4, stream);
    hipMemsetAsync(gcount, 0, (size_t)N_GRAPHS * 4, stream);

    // graph preprocessing
    count_deg<<<(N_EDGES + 255) / 256, 256, 0, stream>>>(src, dst, deg_out, deg_in);
    block_sum<<<NB, 256, 0, stream>>>(deg_in, bsum);
    scan_serial<<<1, 64, 0, stream>>>(bsum, boff, NB);
    node_offsets<<<NB, 256, 0, stream>>>(deg_in, deg_out, boff, row_st, cursor, inv_in, inv_out);
    fill_csr<<<(N_EDGES + 255) / 256, 256, 0, stream>>>(src, dst, cursor, adj);

    // weight conversions + padded small tensors
    conv_bt<<<(NPAD * K1PAD + 255) / 256, 256, 0, stream>>>(W1, B1t, D_IN, D_H, K1PAD);
    conv_bt<<<(NPAD * K2PAD + 255) / 256, 256, 0, stream>>>(W2, B2t, D_H, D_H, K2PAD);
    prep_small<<<3, 256, 0, stream>>>(b1, b2, Wfc, b1p, b2p, wfcp);

    const int AGG_BLOCKS = 8 * (N_NODES / 4);   // 200000; N_NODES divisible by 4

    // layer 1
    gemm_rs<10, true><<<MPAD / 128, 512, 0, stream>>>(x, nullptr, B1t, inv_out, m8, N_NODES);
    agg_shard<false><<<AGG_BLOCKS, 256, 0, stream>>>(m8, row_st, deg_in, adj, inv_in, b1p,
                                                     wfcp, h_bf, zpart);
    // layer 2
    gemm_rs<5, false><<<MPAD / 128, 512, 0, stream>>>(nullptr, h_bf, B2t, inv_out, m8, N_NODES);
    agg_shard<true><<<AGG_BLOCKS, 256, 0, stream>>>(m8, row_st, deg_in, adj, inv_in, b2p,
                                                    wfcp, h_bf, zpart);
    pool_final<<<(N_NODES + 255) / 256, 256, 0, stream>>>((const float4*)zpart, bfc, gid, pooled, gcount);
    finalize<<<(N_GRAPHS * 2 + 255) / 256, 256, 0, stream>>>(pooled, gcount, (float*)d_out);
}

// Round 11
// 1050.376 us; speedup vs baseline: 1.0756x; 1.0756x over previous
//
#include <hip/hip_runtime.h>
#include <hip/hip_bf16.h>
#include <hip/hip_fp8.h>

#define N_NODES 100000
#define N_EDGES 1600000
#define N_GRAPHS 2000
#define D_IN 600
#define D_H 300
#define D_OUT 2

#define NPAD 320        // padded hidden width
#define K1PAD 640
#define K2PAD 320
#define MPAD 100096     // 782 * 128
#define PLANE 4000000   // bytes per column-group plane: 100000 nodes * 40 B

typedef __bf16 bf16;
typedef __bf16 bf16x4 __attribute__((ext_vector_type(4)));
typedef __bf16 bf16x8 __attribute__((ext_vector_type(8)));
typedef float f32x4 __attribute__((ext_vector_type(4)));
typedef float f32x2 __attribute__((ext_vector_type(2)));

__device__ __forceinline__ unsigned char ff8(float f) {
    __hip_fp8_e4m3 t(f); return (unsigned char)t.__x;
}

// ---------------- degree counting ----------------
__global__ __launch_bounds__(256) void count_deg(const int* __restrict__ src,
                                                 const int* __restrict__ dst,
                                                 int* __restrict__ deg_out,
                                                 int* __restrict__ deg_in) {
    int e = blockIdx.x * blockDim.x + threadIdx.x;
    if (e < N_EDGES) {
        atomicAdd(&deg_out[src[e]], 1);
        atomicAdd(&deg_in[dst[e]], 1);
    }
}

// ---------------- per-block sums of deg_in ----------------
__global__ __launch_bounds__(256) void block_sum(const int* __restrict__ deg_in,
                                                 int* __restrict__ bsum) {
    __shared__ int s[256];
    int i = blockIdx.x * 256 + threadIdx.x;
    s[threadIdx.x] = (i < N_NODES) ? deg_in[i] : 0;
    __syncthreads();
    for (int off = 128; off; off >>= 1) {
        if (threadIdx.x < off) s[threadIdx.x] += s[threadIdx.x + off];
        __syncthreads();
    }
    if (threadIdx.x == 0) bsum[blockIdx.x] = s[0];
}

// ---------------- serial scan over block sums ----------------
__global__ void scan_serial(const int* __restrict__ bsum, int* __restrict__ boff, int nb) {
    if (threadIdx.x == 0 && blockIdx.x == 0) {
        int run = 0;
        for (int i = 0; i < nb; ++i) { boff[i] = run; run += bsum[i]; }
    }
}

// ---------------- per-node CSR offsets + inv-sqrt degrees + packed node table ----------------
__global__ __launch_bounds__(256) void node_offsets(const int* __restrict__ deg_in,
                                                    const int* __restrict__ deg_out,
                                                    const int* __restrict__ boff,
                                                    int* __restrict__ row_start,
                                                    int* __restrict__ cursor,
                                                    float* __restrict__ inv_out,
                                                    int4* __restrict__ ntab) {
    __shared__ int s[256];
    int i = blockIdx.x * 256 + threadIdx.x;
    int d = (i < N_NODES) ? deg_in[i] : 0;
    s[threadIdx.x] = d;
    __syncthreads();
    for (int off = 1; off < 256; off <<= 1) {
        int v = 0;
        if (threadIdx.x >= off) v = s[threadIdx.x - off];
        __syncthreads();
        if (threadIdx.x >= off) s[threadIdx.x] += v;
        __syncthreads();
    }
    if (i < N_NODES) {
        int excl = s[threadIdx.x] - d;
        int rs = boff[blockIdx.x] + excl;
        row_start[i] = rs;
        cursor[i] = rs;
        int di = deg_in[i];
        int dout = deg_out[i];
        float invi = (di > 0) ? rsqrtf((float)di) : 0.0f;
        inv_out[i] = (dout > 0) ? rsqrtf((float)dout) : 0.0f;
        ntab[i] = make_int4(rs, di, __float_as_int(invi), 0);
    }
}

// ---------------- fill CSR adjacency ----------------
__global__ __launch_bounds__(256) void fill_csr(const int* __restrict__ src,
                                                const int* __restrict__ dst,
                                                int* __restrict__ cursor,
                                                int* __restrict__ adj) {
    int e = blockIdx.x * blockDim.x + threadIdx.x;
    if (e < N_EDGES) {
        int pos = atomicAdd(&cursor[dst[e]], 1);
        adj[pos] = src[e];
    }
}

// ---------------- W [K][N] fp32 -> Bt [NPAD][Kpad] bf16 ----------------
__global__ __launch_bounds__(256) void conv_bt(const float* __restrict__ W, bf16* __restrict__ Bt,
                                               int K, int N, int Kpad) {
    int idx = blockIdx.x * 256 + threadIdx.x;
    int k = idx % Kpad;
    int n = idx / Kpad;
    if (n >= NPAD) return;
    bf16 v = (bf16)0.0f;
    if (k < K && n < N) v = (bf16)W[(size_t)k * N + n];
    Bt[(size_t)n * Kpad + k] = v;
}

// ---------------- pad bias / Wfc ----------------
__global__ __launch_bounds__(256) void prep_small(const float* __restrict__ b1,
                                                  const float* __restrict__ b2,
                                                  const float* __restrict__ Wfc,
                                                  float* __restrict__ b1p,
                                                  float* __restrict__ b2p,
                                                  float* __restrict__ wfcp) {
    int i = blockIdx.x * 256 + threadIdx.x;
    if (i < NPAD) {
        b1p[i] = (i < D_H) ? b1[i] : 0.f;
        b2p[i] = (i < D_H) ? b2[i] : 0.f;
    }
    if (i < NPAD * 2) {
        wfcp[i] = (i < D_H * 2) ? Wfc[i] : 0.f;
    }
}

// ---------------- reg-staged MFMA GEMM, fp8 PLANAR output ----------------
template<int NK, bool AF32>
__global__ __launch_bounds__(512) void gemm_rs(const float* __restrict__ Af,
                                               const bf16* __restrict__ Ab,
                                               const bf16* __restrict__ Bt,
                                               const float* __restrict__ rowscale,
                                               unsigned char* __restrict__ C8,
                                               int M) {
    __shared__ bf16 As[128 * 64];
    __shared__ bf16 Bs[320 * 64];
    const int tid = threadIdx.x;
    const int lane = tid & 63;
    const int wid = tid >> 6;
    const int wr = wid >> 2;
    const int wc = wid & 3;
    const int blockRow = blockIdx.x * 128;
    const int Kpad = NK * 64;
    const size_t rowBytes = (size_t)Kpad * 2;

    f32x4 acc[4][5] = {};

    int aO[2], aRow[2], aKs[2];
    #pragma unroll
    for (int c = 0; c < 2; ++c) {
        int o = c * 8192 + tid * 16;
        int row = o >> 7;
        int slot = (o >> 4) & 7;
        aO[c] = o; aRow[c] = row; aKs[c] = (slot ^ (row & 7)) * 8;
    }
    int bO[5], bRow[5], bKs[5];
    #pragma unroll
    for (int c = 0; c < 5; ++c) {
        int o = c * 8192 + tid * 16;
        int row = o >> 7;
        int slot = (o >> 4) & 7;
        bO[c] = o; bRow[c] = row; bKs[c] = (slot ^ (row & 7)) * 8;
    }

    float4 fA[2][2];
    bf16x8 sA[2];
    bf16x8 sB[5];

    auto loadTile = [&](int t) {
        #pragma unroll
        for (int c = 0; c < 2; ++c) {
            if (AF32) {
                int gr = blockRow + aRow[c];
                int k = t * 64 + aKs[c];
                if (gr < N_NODES && k < D_IN) {
                    const float* p = Af + (size_t)gr * D_IN + k;
                    fA[c][0] = *(const float4*)p;
                    fA[c][1] = *(const float4*)(p + 4);
                } else {
                    fA[c][0] = make_float4(0.f, 0.f, 0.f, 0.f);
                    fA[c][1] = make_float4(0.f, 0.f, 0.f, 0.f);
                }
            } else {
                const char* g = (const char*)Ab + (size_t)(blockRow + aRow[c]) * rowBytes
                                + (size_t)t * 128 + aKs[c] * 2;
                sA[c] = *(const bf16x8*)g;
            }
        }
        #pragma unroll
        for (int c = 0; c < 5; ++c) {
            const char* g = (const char*)Bt + (size_t)bRow[c] * rowBytes
                            + (size_t)t * 128 + bKs[c] * 2;
            sB[c] = *(const bf16x8*)g;
        }
    };

    loadTile(0);

    for (int t = 0; t < NK; ++t) {
        __syncthreads();
        #pragma unroll
        for (int c = 0; c < 2; ++c) {
            bf16x8 v;
            if (AF32) {
                v[0] = (bf16)fA[c][0].x; v[1] = (bf16)fA[c][0].y;
                v[2] = (bf16)fA[c][0].z; v[3] = (bf16)fA[c][0].w;
                v[4] = (bf16)fA[c][1].x; v[5] = (bf16)fA[c][1].y;
                v[6] = (bf16)fA[c][1].z; v[7] = (bf16)fA[c][1].w;
            } else {
                v = sA[c];
            }
            *(bf16x8*)((char*)As + aO[c]) = v;
        }
        #pragma unroll
        for (int c = 0; c < 5; ++c)
            *(bf16x8*)((char*)Bs + bO[c]) = sB[c];
        __syncthreads();
        if (t + 1 < NK) loadTile(t + 1);
        #pragma unroll
        for (int kk = 0; kk < 2; ++kk) {
            int slot = kk * 4 + (lane >> 4);
            bf16x8 af[4], bfr[5];
            #pragma unroll
            for (int mi = 0; mi < 4; ++mi) {
                int row = wr * 64 + mi * 16 + (lane & 15);
                int addr = row * 128 + ((slot ^ (row & 7)) << 4);
                af[mi] = *(const bf16x8*)((const char*)As + addr);
            }
            #pragma unroll
            for (int ni = 0; ni < 5; ++ni) {
                int row = wc * 80 + ni * 16 + (lane & 15);
                int addr = row * 128 + ((slot ^ (row & 7)) << 4);
                bfr[ni] = *(const bf16x8*)((const char*)Bs + addr);
            }
            #pragma unroll
            for (int mi = 0; mi < 4; ++mi)
                #pragma unroll
                for (int ni = 0; ni < 5; ++ni)
                    acc[mi][ni] = __builtin_amdgcn_mfma_f32_16x16x32_bf16(af[mi], bfr[ni], acc[mi][ni], 0, 0, 0);
        }
    }
    // epilogue: planar fp8 write  (plane g = cols [40g, 40g+40))
    #pragma unroll
    for (int mi = 0; mi < 4; ++mi) {
        #pragma unroll
        for (int i = 0; i < 4; ++i) {
            int gr = blockRow + wr * 64 + mi * 16 + ((lane >> 4) << 2) + i;
            if (gr >= M) continue;
            float sc = rowscale[gr];
            #pragma unroll
            for (int ni = 0; ni < 5; ++ni) {
                int gc = wc * 80 + ni * 16 + (lane & 15);
                int g = gc / 40;
                int o = gc - g * 40;
                C8[(size_t)g * PLANE + (size_t)gr * 40 + o] = ff8(acc[mi][ni][i] * sc);
            }
        }
    }
}

// ---------------- XCD-sharded aggregation, lean version ----------------
// group g = blockIdx&7 -> one XCD per group; plane g (3.81 MiB) fits its L2.
// Wave-per-(node,group): lane = eslot*10 + di; one dword covers 6 edges x 40 B.
// No LDS, no syncthreads: shfl-based reduce. All metadata loads cacheable.
template<bool FUSE_FC>
__global__ __launch_bounds__(256) void agg_shard(const unsigned char* __restrict__ m8,
                                                 const int4* __restrict__ ntab,
                                                 const int* __restrict__ adj,
                                                 const float* __restrict__ biasp,
                                                 const float* __restrict__ wfcp,
                                                 bf16* __restrict__ h,
                                                 float2* __restrict__ zpart) {
    const int lane = threadIdx.x & 63;
    const int wid = threadIdx.x >> 6;
    const int g = blockIdx.x & 7;
    const int node = (blockIdx.x >> 3) * 4 + wid;
    const int4 t = ntab[node];
    const int s = t.x;
    const int d = t.y;
    const float sc = __int_as_float(t.z);
    const int eslot = lane / 10;      // 0..6 (lanes 60..63 -> 6, inactive)
    const int di = lane - eslot * 10; // 0..9
    const bool active = eslot < 6;
    const unsigned char* plane = m8 + (size_t)g * PLANE;
    const int di4 = di * 4;

    // lane-parallel adjacency preload (bpermute source); max degree << 64 in practice
    int adjv = (lane < d) ? adj[s + lane] : 0;

    f32x4 acc = {0.f, 0.f, 0.f, 0.f};
    for (int e = 0; e < d; e += 24) {
        #pragma unroll
        for (int q = 0; q < 4; ++q) {
            int ee = e + q * 6 + eslot;
            bool v = active && (ee < d);
            int idx = __builtin_amdgcn_ds_bpermute(ee << 2, adjv);
            if (v && ee >= 64) idx = adj[s + ee];   // practically never taken
            unsigned int u = 0u;
            if (v) u = *(const unsigned int*)(plane + (size_t)idx * 40 + di4);
            f32x2 lo = __builtin_amdgcn_cvt_pk_f32_fp8(u, false);
            f32x2 hi = __builtin_amdgcn_cvt_pk_f32_fp8(u, true);
            acc[0] += lo[0]; acc[1] += lo[1]; acc[2] += hi[0]; acc[3] += hi[1];
        }
    }

    // reduce over 6 eslots: lanes 0..9 get sum (lanes 60..63 contribute 0)
    f32x4 sum;
    #pragma unroll
    for (int k = 0; k < 4; ++k) {
        float a = acc[k];
        float b = a + __shfl_down(a, 30);     // lanes 0..29 valid
        float c2 = b + __shfl_down(b, 10);    // lanes 0..9: e0+e3+e1+e4
        sum[k] = c2 + __shfl_down(b, 20);     // + e2+e5
    }

    float z0 = 0.f, z1 = 0.f;
    if (lane < 10) {
        int c = g * 40 + lane * 4;
        float4 bq = *(const float4*)(biasp + c);
        float h0 = fmaxf(sum[0] * sc + bq.x, 0.f);
        float h1 = fmaxf(sum[1] * sc + bq.y, 0.f);
        float h2 = fmaxf(sum[2] * sc + bq.z, 0.f);
        float h3 = fmaxf(sum[3] * sc + bq.w, 0.f);
        if (!FUSE_FC) {
            bf16x4 o;
            o[0] = (bf16)h0; o[1] = (bf16)h1; o[2] = (bf16)h2; o[3] = (bf16)h3;
            unsigned long long bits;
            __builtin_memcpy(&bits, &o, 8);
            *(unsigned long long*)(h + (size_t)node * NPAD + c) = bits;
        } else {
            float4 w0 = *(const float4*)(wfcp + c * 2);
            float4 w1 = *(const float4*)(wfcp + c * 2 + 4);
            z0 = h0 * w0.x + h1 * w0.z + h2 * w1.x + h3 * w1.z;
            z1 = h0 * w0.y + h1 * w0.w + h2 * w1.y + h3 * w1.w;
        }
    }
    if (FUSE_FC) {
        // sum z over lanes 0..9 via 16-lane butterfly (lanes 10..15 hold 0)
        #pragma unroll
        for (int m = 8; m; m >>= 1) {
            z0 += __shfl_xor(z0, m, 16);
            z1 += __shfl_xor(z1, m, 16);
        }
        if (lane == 0) {
            zpart[(size_t)node * 8 + g] = make_float2(z0, z1);
        }
    }
}

// ---------------- final: sum group z-partials, softmax, pool ----------------
__global__ __launch_bounds__(256) void pool_final(const float4* __restrict__ zp4,
                                                  const float* __restrict__ bfc,
                                                  const int* __restrict__ gid,
                                                  float* __restrict__ pooled,
                                                  int* __restrict__ gcount) {
    int n = blockIdx.x * 256 + threadIdx.x;
    if (n >= N_NODES) return;
    const float4* p = zp4 + (size_t)n * 4;
    float4 a = p[0], b = p[1], c = p[2], d = p[3];
    float z0 = (a.x + a.z) + (b.x + b.z) + (c.x + c.z) + (d.x + d.z) + bfc[0];
    float z1 = (a.y + a.w) + (b.y + b.w) + (c.y + c.w) + (d.y + d.w) + bfc[1];
    float mx = fmaxf(z0, z1);
    float e0 = __expf(z0 - mx), e1 = __expf(z1 - mx);
    float inv = 1.f / (e0 + e1);
    int g = gid[n];
    atomicAdd(&pooled[g * 2 + 0], e0 * inv);
    atomicAdd(&pooled[g * 2 + 1], e1 * inv);
    atomicAdd(&gcount[g], 1);
}

// ---------------- finalize: divide by counts ----------------
__global__ __launch_bounds__(256) void finalize(const float* __restrict__ pooled,
                                                const int* __restrict__ gcount,
                                                float* __restrict__ out) {
    int i = blockIdx.x * blockDim.x + threadIdx.x;
    if (i < N_GRAPHS * 2) {
        int g = i >> 1;
        float c = (float)max(gcount[g], 1);
        out[i] = pooled[i] / c;
    }
}

extern "C" void kernel_launch(void* const* d_in, const int* in_sizes, int n_in,
                              void* d_out, int out_size, void* d_ws, size_t ws_size,
                              hipStream_t stream) {
    const float* x   = (const float*)d_in[0];
    const float* W1  = (const float*)d_in[1];
    const float* b1  = (const float*)d_in[2];
    const float* W2  = (const float*)d_in[3];
    const float* b2  = (const float*)d_in[4];
    const float* Wfc = (const float*)d_in[5];
    const float* bfc = (const float*)d_in[6];
    const int* src   = (const int*)d_in[7];
    const int* dst   = (const int*)d_in[8];
    const int* gid   = (const int*)d_in[9];

    char* ws = (char*)d_ws;
    size_t off = 0;
    auto alloc = [&](size_t bytes) -> void* {
        void* p = ws + off;
        off = (off + bytes + 255) & ~(size_t)255;
        return p;
    };
    bf16* h_bf            = (bf16*)alloc((size_t)MPAD * NPAD * 2);         // 64.1 MB
    unsigned char* m8     = (unsigned char*)alloc((size_t)8 * PLANE);      // 32 MB planar
    float2* zpart         = (float2*)alloc((size_t)N_NODES * 8 * 8);       // 6.4 MB
    bf16* B1t    = (bf16*)alloc((size_t)NPAD * K1PAD * 2);
    bf16* B2t    = (bf16*)alloc((size_t)NPAD * K2PAD * 2);
    int*   adj      = (int*)alloc((size_t)N_EDGES * 4);
    int*   row_st   = (int*)alloc((size_t)N_NODES * 4);
    int*   cursor   = (int*)alloc((size_t)N_NODES * 4);
    int*   deg_in   = (int*)alloc((size_t)N_NODES * 4);
    int*   deg_out  = (int*)alloc((size_t)N_NODES * 4);
    float* inv_out  = (float*)alloc((size_t)N_NODES * 4);
    int4*  ntab     = (int4*)alloc((size_t)N_NODES * 16);
    const int NB = (N_NODES + 255) / 256;
    int*   bsum     = (int*)alloc((size_t)NB * 4);
    int*   boff     = (int*)alloc((size_t)NB * 4);
    float* pooled   = (float*)alloc((size_t)N_GRAPHS * 2 * 4);
    int*   gcount   = (int*)alloc((size_t)N_GRAPHS * 4);
    float* b1p      = (float*)alloc((size_t)NPAD * 4);
    float* b2p      = (float*)alloc((size_t)NPAD * 4);
    float* wfcp     = (float*)alloc((size_t)NPAD * 2 * 4);

    hipMemsetAsync(deg_in, 0, (size_t)N_NODES * 4, stream);
    hipMemsetAsync(deg_out, 0, (size_t)N_NODES * 4, stream);
    hipMemsetAsync(pooled, 0, (size_t)N_GRAPHS * 2 * 4, stream);
    hipMemsetAsync(gcount, 0, (size_t)N_GRAPHS * 4, stream);

    // graph preprocessing
    count_deg<<<(N_EDGES + 255) / 256, 256, 0, stream>>>(src, dst, deg_out, deg_in);
    block_sum<<<NB, 256, 0, stream>>>(deg_in, bsum);
    scan_serial<<<1, 64, 0, stream>>>(bsum, boff, NB);
    node_offsets<<<NB, 256, 0, stream>>>(deg_in, deg_out, boff, row_st, cursor, inv_out, ntab);
    fill_csr<<<(N_EDGES + 255) / 256, 256, 0, stream>>>(src, dst, cursor, adj);

    // weight conversions + padded small tensors
    conv_bt<<<(NPAD * K1PAD + 255) / 256, 256, 0, stream>>>(W1, B1t, D_IN, D_H, K1PAD);
    conv_bt<<<(NPAD * K2PAD + 255) / 256, 256, 0, stream>>>(W2, B2t, D_H, D_H, K2PAD);
    prep_small<<<3, 256, 0, stream>>>(b1, b2, Wfc, b1p, b2p, wfcp);

    const int AGG_BLOCKS = 8 * (N_NODES / 4);   // 200000

    // layer 1
    gemm_rs<10, true><<<MPAD / 128, 512, 0, stream>>>(x, nullptr, B1t, inv_out, m8, N_NODES);
    agg_shard<false><<<AGG_BLOCKS, 256, 0, stream>>>(m8, ntab, adj, b1p, wfcp, h_bf, zpart);
    // layer 2
    gemm_rs<5, false><<<MPAD / 128, 512, 0, stream>>>(nullptr, h_bf, B2t, inv_out, m8, N_NODES);
    agg_shard<true><<<AGG_BLOCKS, 256, 0, stream>>>(m8, ntab, adj, b2p, wfcp, h_bf, zpart);
    pool_final<<<(N_NODES + 255) / 256, 256, 0, stream>>>((const float4*)zpart, bfc, gid, pooled, gcount);
    finalize<<<(N_GRAPHS * 2 + 255) / 256, 256, 0, stream>>>(pooled, gcount, (float*)d_out);
}

// Round 12
// 882.756 us; speedup vs baseline: 1.2798x; 1.1899x over previous
//
#include <hip/hip_runtime.h>
#include <hip/hip_bf16.h>
#include <hip/hip_fp8.h>

#define N_NODES 100000
#define N_EDGES 1600000
#define N_GRAPHS 2000
#define D_IN 600
#define D_H 300
#define D_OUT 2

#define NPAD 320        // padded hidden width
#define K1PAD 640
#define K2PAD 320
#define MPAD 100096     // 782 * 128
#define PLANE 4000000   // bytes per column-group plane: 100000 nodes * 40 B
#define NPB 24          // nodes per block in agg (4 waves x 6)

typedef __bf16 bf16;
typedef __bf16 bf16x4 __attribute__((ext_vector_type(4)));
typedef __bf16 bf16x8 __attribute__((ext_vector_type(8)));
typedef float f32x4 __attribute__((ext_vector_type(4)));
typedef float f32x2 __attribute__((ext_vector_type(2)));

__device__ __forceinline__ unsigned char ff8(float f) {
    __hip_fp8_e4m3 t(f); return (unsigned char)t.__x;
}

// ---------------- degree counting ----------------
__global__ __launch_bounds__(256) void count_deg(const int* __restrict__ src,
                                                 const int* __restrict__ dst,
                                                 int* __restrict__ deg_out,
                                                 int* __restrict__ deg_in) {
    int e = blockIdx.x * blockDim.x + threadIdx.x;
    if (e < N_EDGES) {
        atomicAdd(&deg_out[src[e]], 1);
        atomicAdd(&deg_in[dst[e]], 1);
    }
}

// ---------------- per-block sums of deg_in ----------------
__global__ __launch_bounds__(256) void block_sum(const int* __restrict__ deg_in,
                                                 int* __restrict__ bsum) {
    __shared__ int s[256];
    int i = blockIdx.x * 256 + threadIdx.x;
    s[threadIdx.x] = (i < N_NODES) ? deg_in[i] : 0;
    __syncthreads();
    for (int off = 128; off; off >>= 1) {
        if (threadIdx.x < off) s[threadIdx.x] += s[threadIdx.x + off];
        __syncthreads();
    }
    if (threadIdx.x == 0) bsum[blockIdx.x] = s[0];
}

// ---------------- serial scan over block sums ----------------
__global__ void scan_serial(const int* __restrict__ bsum, int* __restrict__ boff, int nb) {
    if (threadIdx.x == 0 && blockIdx.x == 0) {
        int run = 0;
        for (int i = 0; i < nb; ++i) { boff[i] = run; run += bsum[i]; }
    }
}

// ---------------- per-node CSR offsets + inv-sqrt degrees + packed node table ----------------
__global__ __launch_bounds__(256) void node_offsets(const int* __restrict__ deg_in,
                                                    const int* __restrict__ deg_out,
                                                    const int* __restrict__ boff,
                                                    int* __restrict__ row_start,
                                                    int* __restrict__ cursor,
                                                    float* __restrict__ inv_out,
                                                    int4* __restrict__ ntab) {
    __shared__ int s[256];
    int i = blockIdx.x * 256 + threadIdx.x;
    int d = (i < N_NODES) ? deg_in[i] : 0;
    s[threadIdx.x] = d;
    __syncthreads();
    for (int off = 1; off < 256; off <<= 1) {
        int v = 0;
        if (threadIdx.x >= off) v = s[threadIdx.x - off];
        __syncthreads();
        if (threadIdx.x >= off) s[threadIdx.x] += v;
        __syncthreads();
    }
    if (i < N_NODES) {
        int excl = s[threadIdx.x] - d;
        int rs = boff[blockIdx.x] + excl;
        row_start[i] = rs;
        cursor[i] = rs;
        int di = deg_in[i];
        int dout = deg_out[i];
        float invi = (di > 0) ? rsqrtf((float)di) : 0.0f;
        inv_out[i] = (dout > 0) ? rsqrtf((float)dout) : 0.0f;
        ntab[i] = make_int4(rs, di, __float_as_int(invi), 0);
    }
    if (i == 0) ntab[N_NODES] = make_int4(N_EDGES, 0, 0, 0);   // sentinel
}

// ---------------- fill CSR adjacency ----------------
__global__ __launch_bounds__(256) void fill_csr(const int* __restrict__ src,
                                                const int* __restrict__ dst,
                                                int* __restrict__ cursor,
                                                int* __restrict__ adj) {
    int e = blockIdx.x * blockDim.x + threadIdx.x;
    if (e < N_EDGES) {
        int pos = atomicAdd(&cursor[dst[e]], 1);
        adj[pos] = src[e];
    }
}

// ---------------- W [K][N] fp32 -> Bt [NPAD][Kpad] bf16 ----------------
__global__ __launch_bounds__(256) void conv_bt(const float* __restrict__ W, bf16* __restrict__ Bt,
                                               int K, int N, int Kpad) {
    int idx = blockIdx.x * 256 + threadIdx.x;
    int k = idx % Kpad;
    int n = idx / Kpad;
    if (n >= NPAD) return;
    bf16 v = (bf16)0.0f;
    if (k < K && n < N) v = (bf16)W[(size_t)k * N + n];
    Bt[(size_t)n * Kpad + k] = v;
}

// ---------------- pad bias / Wfc ----------------
__global__ __launch_bounds__(256) void prep_small(const float* __restrict__ b1,
                                                  const float* __restrict__ b2,
                                                  const float* __restrict__ Wfc,
                                                  float* __restrict__ b1p,
                                                  float* __restrict__ b2p,
                                                  float* __restrict__ wfcp) {
    int i = blockIdx.x * 256 + threadIdx.x;
    if (i < NPAD) {
        b1p[i] = (i < D_H) ? b1[i] : 0.f;
        b2p[i] = (i < D_H) ? b2[i] : 0.f;
    }
    if (i < NPAD * 2) {
        wfcp[i] = (i < D_H * 2) ? Wfc[i] : 0.f;
    }
}

// ---------------- reg-staged MFMA GEMM, fp8 PLANAR output ----------------
template<int NK, bool AF32>
__global__ __launch_bounds__(512) void gemm_rs(const float* __restrict__ Af,
                                               const bf16* __restrict__ Ab,
                                               const bf16* __restrict__ Bt,
                                               const float* __restrict__ rowscale,
                                               unsigned char* __restrict__ C8,
                                               int M) {
    __shared__ bf16 As[128 * 64];
    __shared__ bf16 Bs[320 * 64];
    const int tid = threadIdx.x;
    const int lane = tid & 63;
    const int wid = tid >> 6;
    const int wr = wid >> 2;
    const int wc = wid & 3;
    const int blockRow = blockIdx.x * 128;
    const int Kpad = NK * 64;
    const size_t rowBytes = (size_t)Kpad * 2;

    f32x4 acc[4][5] = {};

    int aO[2], aRow[2], aKs[2];
    #pragma unroll
    for (int c = 0; c < 2; ++c) {
        int o = c * 8192 + tid * 16;
        int row = o >> 7;
        int slot = (o >> 4) & 7;
        aO[c] = o; aRow[c] = row; aKs[c] = (slot ^ (row & 7)) * 8;
    }
    int bO[5], bRow[5], bKs[5];
    #pragma unroll
    for (int c = 0; c < 5; ++c) {
        int o = c * 8192 + tid * 16;
        int row = o >> 7;
        int slot = (o >> 4) & 7;
        bO[c] = o; bRow[c] = row; bKs[c] = (slot ^ (row & 7)) * 8;
    }

    float4 fA[2][2];
    bf16x8 sA[2];
    bf16x8 sB[5];

    auto loadTile = [&](int t) {
        #pragma unroll
        for (int c = 0; c < 2; ++c) {
            if (AF32) {
                int gr = blockRow + aRow[c];
                int k = t * 64 + aKs[c];
                if (gr < N_NODES && k < D_IN) {
                    const float* p = Af + (size_t)gr * D_IN + k;
                    fA[c][0] = *(const float4*)p;
                    fA[c][1] = *(const float4*)(p + 4);
                } else {
                    fA[c][0] = make_float4(0.f, 0.f, 0.f, 0.f);
                    fA[c][1] = make_float4(0.f, 0.f, 0.f, 0.f);
                }
            } else {
                const char* g = (const char*)Ab + (size_t)(blockRow + aRow[c]) * rowBytes
                                + (size_t)t * 128 + aKs[c] * 2;
                sA[c] = *(const bf16x8*)g;
            }
        }
        #pragma unroll
        for (int c = 0; c < 5; ++c) {
            const char* g = (const char*)Bt + (size_t)bRow[c] * rowBytes
                            + (size_t)t * 128 + bKs[c] * 2;
            sB[c] = *(const bf16x8*)g;
        }
    };

    loadTile(0);

    for (int t = 0; t < NK; ++t) {
        __syncthreads();
        #pragma unroll
        for (int c = 0; c < 2; ++c) {
            bf16x8 v;
            if (AF32) {
                v[0] = (bf16)fA[c][0].x; v[1] = (bf16)fA[c][0].y;
                v[2] = (bf16)fA[c][0].z; v[3] = (bf16)fA[c][0].w;
                v[4] = (bf16)fA[c][1].x; v[5] = (bf16)fA[c][1].y;
                v[6] = (bf16)fA[c][1].z; v[7] = (bf16)fA[c][1].w;
            } else {
                v = sA[c];
            }
            *(bf16x8*)((char*)As + aO[c]) = v;
        }
        #pragma unroll
        for (int c = 0; c < 5; ++c)
            *(bf16x8*)((char*)Bs + bO[c]) = sB[c];
        __syncthreads();
        if (t + 1 < NK) loadTile(t + 1);
        #pragma unroll
        for (int kk = 0; kk < 2; ++kk) {
            int slot = kk * 4 + (lane >> 4);
            bf16x8 af[4], bfr[5];
            #pragma unroll
            for (int mi = 0; mi < 4; ++mi) {
                int row = wr * 64 + mi * 16 + (lane & 15);
                int addr = row * 128 + ((slot ^ (row & 7)) << 4);
                af[mi] = *(const bf16x8*)((const char*)As + addr);
            }
            #pragma unroll
            for (int ni = 0; ni < 5; ++ni) {
                int row = wc * 80 + ni * 16 + (lane & 15);
                int addr = row * 128 + ((slot ^ (row & 7)) << 4);
                bfr[ni] = *(const bf16x8*)((const char*)Bs + addr);
            }
            #pragma unroll
            for (int mi = 0; mi < 4; ++mi)
                #pragma unroll
                for (int ni = 0; ni < 5; ++ni)
                    acc[mi][ni] = __builtin_amdgcn_mfma_f32_16x16x32_bf16(af[mi], bfr[ni], acc[mi][ni], 0, 0, 0);
        }
    }
    // epilogue: planar fp8 write  (plane g = cols [40g, 40g+40))
    #pragma unroll
    for (int mi = 0; mi < 4; ++mi) {
        #pragma unroll
        for (int i = 0; i < 4; ++i) {
            int gr = blockRow + wr * 64 + mi * 16 + ((lane >> 4) << 2) + i;
            if (gr >= M) continue;
            float sc = rowscale[gr];
            #pragma unroll
            for (int ni = 0; ni < 5; ++ni) {
                int gc = wc * 80 + ni * 16 + (lane & 15);
                int g = gc / 40;
                int o = gc - g * 40;
                C8[(size_t)g * PLANE + (size_t)gr * 40 + o] = ff8(acc[mi][ni][i] * sc);
            }
        }
    }
}

// ---------------- XCD-sharded aggregation, serial-lane version ----------------
// group g = blockIdx&7 -> one XCD per group; plane g (3.81 MiB) resides in its L2.
// Block = 24 nodes x 1 group. Wave = 6 nodes x 10 lanes; lane owns (node, 4-col chunk)
// and walks the node's edges serially. Block's CSR slice staged in LDS (nontemporal).
template<bool FUSE_FC>
__global__ __launch_bounds__(256) void agg_shard(const unsigned char* __restrict__ m8,
                                                 const int4* __restrict__ ntab,
                                                 const int* __restrict__ adj,
                                                 const float* __restrict__ biasp,
                                                 const float* __restrict__ wfcp,
                                                 bf16* __restrict__ h,
                                                 float2* __restrict__ zpart) {
    __shared__ int adjL[1024];
    __shared__ int4 ntabL[NPB + 1];
    const int tid = threadIdx.x;
    const int lane = tid & 63;
    const int wid = tid >> 6;
    const int g = blockIdx.x & 7;
    const int nodeBase = (blockIdx.x >> 3) * NPB;

    if (tid <= NPB) {
        int gn = nodeBase + tid;
        if (gn > N_NODES) gn = N_NODES;
        ntabL[tid] = ntab[gn];
    }
    __syncthreads();
    const int eBase = ntabL[0].x;
    const int eCount = min(ntabL[NPB].x - eBase, 1024);
    for (int i = tid; i < eCount; i += 256)
        adjL[i] = __builtin_nontemporal_load(adj + eBase + i);
    __syncthreads();

    const int nl = lane / 10;            // 0..6 (lanes 60..63 -> 6, inactive)
    const int k = lane - nl * 10;        // 0..9
    const int ln = wid * 6 + nl;         // local node 0..23 (24 = invalid)
    const bool laneActive = (nl < 6) && (nodeBase + ln < N_NODES);
    const int4 nt = ntabL[laneActive ? ln : NPB];
    const int s = nt.x;
    const int d = laneActive ? nt.y : 0;
    const float sc = __int_as_float(nt.z);
    const unsigned char* plane = m8 + (size_t)g * PLANE;
    const int sL = s - eBase;
    const int k4 = k * 4;

    f32x4 acc = {0.f, 0.f, 0.f, 0.f};
    for (int e = 0; e < d; e += 4) {
        unsigned int u[4] = {0u, 0u, 0u, 0u};
        #pragma unroll
        for (int q = 0; q < 4; ++q) {
            int ee = e + q;
            if (ee < d) {
                int li = sL + ee;
                int idx = (li < eCount) ? adjL[li] : adj[s + ee];
                u[q] = *(const unsigned int*)(plane + (size_t)idx * 40 + k4);
            }
        }
        #pragma unroll
        for (int q = 0; q < 4; ++q) {
            f32x2 lo = __builtin_amdgcn_cvt_pk_f32_fp8(u[q], false);
            f32x2 hi = __builtin_amdgcn_cvt_pk_f32_fp8(u[q], true);
            acc[0] += lo[0]; acc[1] += lo[1]; acc[2] += hi[0]; acc[3] += hi[1];
        }
    }

    const int c = g * 40 + k4;
    float4 bq = *(const float4*)(biasp + c);
    float h0 = fmaxf(acc[0] * sc + bq.x, 0.f);
    float h1 = fmaxf(acc[1] * sc + bq.y, 0.f);
    float h2 = fmaxf(acc[2] * sc + bq.z, 0.f);
    float h3 = fmaxf(acc[3] * sc + bq.w, 0.f);

    if (!FUSE_FC) {
        if (laneActive) {
            bf16x4 o;
            o[0] = (bf16)h0; o[1] = (bf16)h1; o[2] = (bf16)h2; o[3] = (bf16)h3;
            unsigned long long bits;
            __builtin_memcpy(&bits, &o, 8);
            int node = nodeBase + ln;
            __builtin_nontemporal_store(bits,
                (unsigned long long*)(h + (size_t)node * NPAD + c));
        }
    } else {
        float4 w0 = *(const float4*)(wfcp + c * 2);
        float4 w1 = *(const float4*)(wfcp + c * 2 + 4);
        float z0 = h0 * w0.x + h1 * w0.z + h2 * w1.x + h3 * w1.z;
        float z1 = h0 * w0.y + h1 * w0.w + h2 * w1.y + h3 * w1.w;
        // reduce over the 10 lanes of this node
        float t0 = __shfl(z0, lane + 5);
        float t1 = __shfl(z1, lane + 5);
        if (k < 5) { z0 += t0; z1 += t1; }
        int base = lane - k;
        float a1 = __shfl(z0, base + 1), a2 = __shfl(z0, base + 2);
        float a3 = __shfl(z0, base + 3), a4 = __shfl(z0, base + 4);
        float b1 = __shfl(z1, base + 1), b2 = __shfl(z1, base + 2);
        float b3 = __shfl(z1, base + 3), b4 = __shfl(z1, base + 4);
        if (k == 0 && laneActive) {
            z0 += (a1 + a2) + (a3 + a4);
            z1 += (b1 + b2) + (b3 + b4);
            f32x2 zp = {z0, z1};
            unsigned long long bits;
            __builtin_memcpy(&bits, &zp, 8);
            int node = nodeBase + ln;
            __builtin_nontemporal_store(bits,
                (unsigned long long*)(zpart + (size_t)node * 8 + g));
        }
    }
}

// ---------------- final: sum group z-partials, softmax, pool ----------------
__global__ __launch_bounds__(256) void pool_final(const float4* __restrict__ zp4,
                                                  const float* __restrict__ bfc,
                                                  const int* __restrict__ gid,
                                                  float* __restrict__ pooled,
                                                  int* __restrict__ gcount) {
    int n = blockIdx.x * 256 + threadIdx.x;
    if (n >= N_NODES) return;
    const float4* p = zp4 + (size_t)n * 4;
    float4 a = p[0], b = p[1], c = p[2], d = p[3];
    float z0 = (a.x + a.z) + (b.x + b.z) + (c.x + c.z) + (d.x + d.z) + bfc[0];
    float z1 = (a.y + a.w) + (b.y + b.w) + (c.y + c.w) + (d.y + d.w) + bfc[1];
    float mx = fmaxf(z0, z1);
    float e0 = __expf(z0 - mx), e1 = __expf(z1 - mx);
    float inv = 1.f / (e0 + e1);
    int g = gid[n];
    atomicAdd(&pooled[g * 2 + 0], e0 * inv);
    atomicAdd(&pooled[g * 2 + 1], e1 * inv);
    atomicAdd(&gcount[g], 1);
}

// ---------------- finalize: divide by counts ----------------
__global__ __launch_bounds__(256) void finalize(const float* __restrict__ pooled,
                                                const int* __restrict__ gcount,
                                                float* __restrict__ out) {
    int i = blockIdx.x * blockDim.x + threadIdx.x;
    if (i < N_GRAPHS * 2) {
        int g = i >> 1;
        float c = (float)max(gcount[g], 1);
        out[i] = pooled[i] / c;
    }
}

extern "C" void kernel_launch(void* const* d_in, const int* in_sizes, int n_in,
                              void* d_out, int out_size, void* d_ws, size_t ws_size,
                              hipStream_t stream) {
    const float* x   = (const float*)d_in[0];
    const float* W1  = (const float*)d_in[1];
    const float* b1  = (const float*)d_in[2];
    const float* W2  = (const float*)d_in[3];
    const float* b2  = (const float*)d_in[4];
    const float* Wfc = (const float*)d_in[5];
    const float* bfc = (const float*)d_in[6];
    const int* src   = (const int*)d_in[7];
    const int* dst   = (const int*)d_in[8];
    const int* gid   = (const int*)d_in[9];

    char* ws = (char*)d_ws;
    size_t off = 0;
    auto alloc = [&](size_t bytes) -> void* {
        void* p = ws + off;
        off = (off + bytes + 255) & ~(size_t)255;
        return p;
    };
    bf16* h_bf            = (bf16*)alloc((size_t)MPAD * NPAD * 2);         // 64.1 MB
    unsigned char* m8     = (unsigned char*)alloc((size_t)8 * PLANE);      // 32 MB planar
    float2* zpart         = (float2*)alloc((size_t)N_NODES * 8 * 8);       // 6.4 MB
    bf16* B1t    = (bf16*)alloc((size_t)NPAD * K1PAD * 2);
    bf16* B2t    = (bf16*)alloc((size_t)NPAD * K2PAD * 2);
    int*   adj      = (int*)alloc((size_t)N_EDGES * 4);
    int*   row_st   = (int*)alloc((size_t)N_NODES * 4);
    int*   cursor   = (int*)alloc((size_t)N_NODES * 4);
    int*   deg_in   = (int*)alloc((size_t)N_NODES * 4);
    int*   deg_out  = (int*)alloc((size_t)N_NODES * 4);
    float* inv_out  = (float*)alloc((size_t)N_NODES * 4);
    int4*  ntab     = (int4*)alloc((size_t)(N_NODES + 1) * 16);
    const int NB = (N_NODES + 255) / 256;
    int*   bsum     = (int*)alloc((size_t)NB * 4);
    int*   boff     = (int*)alloc((size_t)NB * 4);
    float* pooled   = (float*)alloc((size_t)N_GRAPHS * 2 * 4);
    int*   gcount   = (int*)alloc((size_t)N_GRAPHS * 4);
    float* b1p      = (float*)alloc((size_t)NPAD * 4);
    float* b2p      = (float*)alloc((size_t)NPAD * 4);
    float* wfcp     = (float*)alloc((size_t)NPAD * 2 * 4);

    hipMemsetAsync(deg_in, 0, (size_t)N_NODES * 4, stream);
    hipMemsetAsync(deg_out, 0, (size_t)N_NODES * 4, stream);
    hipMemsetAsync(pooled, 0, (size_t)N_GRAPHS * 2 * 4, stream);
    hipMemsetAsync(gcount, 0, (size_t)N_GRAPHS * 4, stream);

    // graph preprocessing
    count_deg<<<(N_EDGES + 255) / 256, 256, 0, stream>>>(src, dst, deg_out, deg_in);
    block_sum<<<NB, 256, 0, stream>>>(deg_in, bsum);
    scan_serial<<<1, 64, 0, stream>>>(bsum, boff, NB);
    node_offsets<<<NB, 256, 0, stream>>>(deg_in, deg_out, boff, row_st, cursor, inv_out, ntab);
    fill_csr<<<(N_EDGES + 255) / 256, 256, 0, stream>>>(src, dst, cursor, adj);

    // weight conversions + padded small tensors
    conv_bt<<<(NPAD * K1PAD + 255) / 256, 256, 0, stream>>>(W1, B1t, D_IN, D_H, K1PAD);
    conv_bt<<<(NPAD * K2PAD + 255) / 256, 256, 0, stream>>>(W2, B2t, D_H, D_H, K2PAD);
    prep_small<<<3, 256, 0, stream>>>(b1, b2, Wfc, b1p, b2p, wfcp);

    const int AGG_BLOCKS = ((N_NODES + NPB - 1) / NPB) * 8;   // 4167 * 8 = 33336

    // layer 1
    gemm_rs<10, true><<<MPAD / 128, 512, 0, stream>>>(x, nullptr, B1t, inv_out, m8, N_NODES);
    agg_shard<false><<<AGG_BLOCKS, 256, 0, stream>>>(m8, ntab, adj, b1p, wfcp, h_bf, zpart);
    // layer 2
    gemm_rs<5, false><<<MPAD / 128, 512, 0, stream>>>(nullptr, h_bf, B2t, inv_out, m8, N_NODES);
    agg_shard<true><<<AGG_BLOCKS, 256, 0, stream>>>(m8, ntab, adj, b2p, wfcp, h_bf, zpart);
    pool_final<<<(N_NODES + 255) / 256, 256, 0, stream>>>((const float4*)zpart, bfc, gid, pooled, gcount);
    finalize<<<(N_GRAPHS * 2 + 255) / 256, 256, 0, stream>>>(pooled, gcount, (float*)d_out);
}

// Round 13
// 685.554 us; speedup vs baseline: 1.6479x; 1.2877x over previous
//
#include <hip/hip_runtime.h>
#include <hip/hip_bf16.h>
#include <hip/hip_fp8.h>

#define N_NODES 100000
#define N_EDGES 1600000
#define N_GRAPHS 2000
#define D_IN 600
#define D_H 300
#define D_OUT 2

#define NPAD 320        // padded hidden width (multiple of 64)
#define K1PAD 640       // padded K for layer-1 GEMM
#define K2PAD 320       // padded K for layer-2 GEMM
#define MPAD 100096     // 782 * 128

typedef __bf16 bf16;
typedef __bf16 bf16x8 __attribute__((ext_vector_type(8)));
typedef float f32x4 __attribute__((ext_vector_type(4)));
typedef float f32x2 __attribute__((ext_vector_type(2)));

__device__ __forceinline__ unsigned char ff8(float f) {
    __hip_fp8_e4m3 t(f); return (unsigned char)t.__x;
}

// ---------------- degree counting ----------------
__global__ __launch_bounds__(256) void count_deg(const int* __restrict__ src,
                                                 const int* __restrict__ dst,
                                                 int* __restrict__ deg_out,
                                                 int* __restrict__ deg_in) {
    int e = blockIdx.x * blockDim.x + threadIdx.x;
    if (e < N_EDGES) {
        atomicAdd(&deg_out[src[e]], 1);
        atomicAdd(&deg_in[dst[e]], 1);
    }
}

// ---------------- per-block sums of deg_in ----------------
__global__ __launch_bounds__(256) void block_sum(const int* __restrict__ deg_in,
                                                 int* __restrict__ bsum) {
    __shared__ int s[256];
    int i = blockIdx.x * 256 + threadIdx.x;
    s[threadIdx.x] = (i < N_NODES) ? deg_in[i] : 0;
    __syncthreads();
    for (int off = 128; off; off >>= 1) {
        if (threadIdx.x < off) s[threadIdx.x] += s[threadIdx.x + off];
        __syncthreads();
    }
    if (threadIdx.x == 0) bsum[blockIdx.x] = s[0];
}

// ---------------- serial scan over block sums ----------------
__global__ void scan_serial(const int* __restrict__ bsum, int* __restrict__ boff, int nb) {
    if (threadIdx.x == 0 && blockIdx.x == 0) {
        int run = 0;
        for (int i = 0; i < nb; ++i) { boff[i] = run; run += bsum[i]; }
    }
}

// ---------------- per-node CSR offsets + inv-sqrt degrees ----------------
__global__ __launch_bounds__(256) void node_offsets(const int* __restrict__ deg_in,
                                                    const int* __restrict__ deg_out,
                                                    const int* __restrict__ boff,
                                                    int* __restrict__ row_start,
                                                    int* __restrict__ cursor,
                                                    float* __restrict__ inv_in,
                                                    float* __restrict__ inv_out) {
    __shared__ int s[256];
    int i = blockIdx.x * 256 + threadIdx.x;
    int d = (i < N_NODES) ? deg_in[i] : 0;
    s[threadIdx.x] = d;
    __syncthreads();
    for (int off = 1; off < 256; off <<= 1) {
        int v = 0;
        if (threadIdx.x >= off) v = s[threadIdx.x - off];
        __syncthreads();
        if (threadIdx.x >= off) s[threadIdx.x] += v;
        __syncthreads();
    }
    if (i < N_NODES) {
        int excl = s[threadIdx.x] - d;
        int rs = boff[blockIdx.x] + excl;
        row_start[i] = rs;
        cursor[i] = rs;
        int di = deg_in[i];
        int dout = deg_out[i];
        inv_in[i]  = (di   > 0) ? rsqrtf((float)di)   : 0.0f;
        inv_out[i] = (dout > 0) ? rsqrtf((float)dout) : 0.0f;
    }
}

// ---------------- fill CSR adjacency ----------------
__global__ __launch_bounds__(256) void fill_csr(const int* __restrict__ src,
                                                const int* __restrict__ dst,
                                                int* __restrict__ cursor,
                                                int* __restrict__ adj) {
    int e = blockIdx.x * blockDim.x + threadIdx.x;
    if (e < N_EDGES) {
        int pos = atomicAdd(&cursor[dst[e]], 1);
        adj[pos] = src[e];
    }
}

// ---------------- W [K][N] fp32 -> Bt [NPAD][Kpad] bf16 ----------------
__global__ __launch_bounds__(256) void conv_bt(const float* __restrict__ W, bf16* __restrict__ Bt,
                                               int K, int N, int Kpad) {
    int idx = blockIdx.x * 256 + threadIdx.x;
    int k = idx % Kpad;
    int n = idx / Kpad;
    if (n >= NPAD) return;
    bf16 v = (bf16)0.0f;
    if (k < K && n < N) v = (bf16)W[(size_t)k * N + n];
    Bt[(size_t)n * Kpad + k] = v;
}

// ---------------- pad bias / Wfc ----------------
__global__ __launch_bounds__(256) void prep_small(const float* __restrict__ b1,
                                                  const float* __restrict__ b2,
                                                  const float* __restrict__ Wfc,
                                                  float* __restrict__ b1p,
                                                  float* __restrict__ b2p,
                                                  float* __restrict__ wfcp) {
    int i = blockIdx.x * 256 + threadIdx.x;
    if (i < NPAD) {
        b1p[i] = (i < D_H) ? b1[i] : 0.f;
        b2p[i] = (i < D_H) ? b2[i] : 0.f;
    }
    if (i < NPAD * 2) {
        wfcp[i] = (i < D_H * 2) ? Wfc[i] : 0.f;
    }
}

// ---------------- reg-staged MFMA GEMM, 128x160 tile, 4 waves, 36 KB LDS ----------------
// Higher occupancy than the 128x320/512-thread version: 4 blocks/CU LDS-limit, 2x grid.
template<int NK, bool AF32>
__global__ __launch_bounds__(256) void gemm_rs(const float* __restrict__ Af,
                                               const bf16* __restrict__ Ab,
                                               const bf16* __restrict__ Bt,
                                               const float* __restrict__ rowscale,
                                               unsigned char* __restrict__ C8,
                                               int M) {
    __shared__ bf16 As[128 * 64];   // 16 KB
    __shared__ bf16 Bs[160 * 64];   // 20 KB
    const int tid = threadIdx.x;
    const int lane = tid & 63;
    const int wid = tid >> 6;       // 0..3
    const int wr = wid >> 1;        // 0..1 -> 64-row half
    const int wc = wid & 1;         // 0..1 -> 80-col half
    const int blockRow = blockIdx.x * 128;
    const int blockCol = blockIdx.y * 160;
    const int Kpad = NK * 64;
    const size_t rowBytes = (size_t)Kpad * 2;

    f32x4 acc[4][5] = {};

    // staging geometry: 256 thr x 16 B = 4 KB per chunk; A 4 chunks, B 5 chunks
    int aO[4], aRow[4], aKs[4];
    #pragma unroll
    for (int c = 0; c < 4; ++c) {
        int o = c * 4096 + tid * 16;
        int row = o >> 7;
        int slot = (o >> 4) & 7;
        aO[c] = o; aRow[c] = row; aKs[c] = (slot ^ (row & 7)) * 8;
    }
    int bO[5], bRow[5], bKs[5];
    #pragma unroll
    for (int c = 0; c < 5; ++c) {
        int o = c * 4096 + tid * 16;
        int row = o >> 7;
        int slot = (o >> 4) & 7;
        bO[c] = o; bRow[c] = row; bKs[c] = (slot ^ (row & 7)) * 8;
    }

    float4 fA[4][2];   // f32-A staging regs
    bf16x8 sA[4];      // bf16-A staging regs
    bf16x8 sB[5];      // B staging regs

    auto loadTile = [&](int t) {
        #pragma unroll
        for (int c = 0; c < 4; ++c) {
            if (AF32) {
                int gr = blockRow + aRow[c];
                int k = t * 64 + aKs[c];
                if (gr < N_NODES && k < D_IN) {
                    const float* p = Af + (size_t)gr * D_IN + k;
                    fA[c][0] = *(const float4*)p;
                    fA[c][1] = *(const float4*)(p + 4);
                } else {
                    fA[c][0] = make_float4(0.f, 0.f, 0.f, 0.f);
                    fA[c][1] = make_float4(0.f, 0.f, 0.f, 0.f);
                }
            } else {
                const char* g = (const char*)Ab + (size_t)(blockRow + aRow[c]) * rowBytes
                                + (size_t)t * 128 + aKs[c] * 2;
                sA[c] = *(const bf16x8*)g;
            }
        }
        #pragma unroll
        for (int c = 0; c < 5; ++c) {
            const char* g = (const char*)Bt + (size_t)(blockCol + bRow[c]) * rowBytes
                            + (size_t)t * 128 + bKs[c] * 2;
            sB[c] = *(const bf16x8*)g;
        }
    };

    loadTile(0);

    for (int t = 0; t < NK; ++t) {
        __syncthreads();   // prev tile's LDS reads done
        #pragma unroll
        for (int c = 0; c < 4; ++c) {
            bf16x8 v;
            if (AF32) {
                v[0] = (bf16)fA[c][0].x; v[1] = (bf16)fA[c][0].y;
                v[2] = (bf16)fA[c][0].z; v[3] = (bf16)fA[c][0].w;
                v[4] = (bf16)fA[c][1].x; v[5] = (bf16)fA[c][1].y;
                v[6] = (bf16)fA[c][1].z; v[7] = (bf16)fA[c][1].w;
            } else {
                v = sA[c];
            }
            *(bf16x8*)((char*)As + aO[c]) = v;
        }
        #pragma unroll
        for (int c = 0; c < 5; ++c)
            *(bf16x8*)((char*)Bs + bO[c]) = sB[c];
        __syncthreads();   // tile visible
        if (t + 1 < NK) loadTile(t + 1);   // next tile in flight under MFMA
        #pragma unroll
        for (int kk = 0; kk < 2; ++kk) {
            int slot = kk * 4 + (lane >> 4);
            bf16x8 af[4], bfr[5];
            #pragma unroll
            for (int mi = 0; mi < 4; ++mi) {
                int row = wr * 64 + mi * 16 + (lane & 15);
                int addr = row * 128 + ((slot ^ (row & 7)) << 4);
                af[mi] = *(const bf16x8*)((const char*)As + addr);
            }
            #pragma unroll
            for (int ni = 0; ni < 5; ++ni) {
                int row = wc * 80 + ni * 16 + (lane & 15);
                int addr = row * 128 + ((slot ^ (row & 7)) << 4);
                bfr[ni] = *(const bf16x8*)((const char*)Bs + addr);
            }
            #pragma unroll
            for (int mi = 0; mi < 4; ++mi)
                #pragma unroll
                for (int ni = 0; ni < 5; ++ni)
                    acc[mi][ni] = __builtin_amdgcn_mfma_f32_16x16x32_bf16(af[mi], bfr[ni], acc[mi][ni], 0, 0, 0);
        }
    }
    // epilogue: row-major fp8
    #pragma unroll
    for (int mi = 0; mi < 4; ++mi) {
        #pragma unroll
        for (int i = 0; i < 4; ++i) {
            int gr = blockRow + wr * 64 + mi * 16 + ((lane >> 4) << 2) + i;
            if (gr >= M) continue;
            float sc = rowscale[gr];
            #pragma unroll
            for (int ni = 0; ni < 5; ++ni) {
                int gc = blockCol + wc * 80 + ni * 16 + (lane & 15);
                C8[(size_t)gr * NPAD + gc] = ff8(acc[mi][ni][i] * sc);
            }
        }
    }
}

// ---------------- fp8 gather core: wave-per-node, HW byte-select converts, unroll x8 ----------
__device__ __forceinline__ void gather_fp8(const unsigned char* __restrict__ m8,
                                           const int* __restrict__ adj,
                                           int s, int d, int lane, float acc[5]) {
    const int cb = lane * 4;
    const int c4 = 256 + lane;
    int e = 0;
    for (; e + 8 <= d; e += 8) {
        unsigned int u[8], b[8];
        #pragma unroll
        for (int j = 0; j < 8; ++j) {
            const unsigned char* r = m8 + (size_t)adj[s + e + j] * NPAD;
            u[j] = *(const unsigned int*)(r + cb);
            b[j] = r[c4];
        }
        #pragma unroll
        for (int j = 0; j < 8; ++j) {
            f32x2 lo = __builtin_amdgcn_cvt_pk_f32_fp8(u[j], false);
            f32x2 hi = __builtin_amdgcn_cvt_pk_f32_fp8(u[j], true);
            acc[0] += lo[0]; acc[1] += lo[1]; acc[2] += hi[0]; acc[3] += hi[1];
            acc[4] += __builtin_amdgcn_cvt_f32_fp8(b[j], 0);
        }
    }
    if (e + 4 <= d) {
        unsigned int u[4], b[4];
        #pragma unroll
        for (int j = 0; j < 4; ++j) {
            const unsigned char* r = m8 + (size_t)adj[s + e + j] * NPAD;
            u[j] = *(const unsigned int*)(r + cb);
            b[j] = r[c4];
        }
        #pragma unroll
        for (int j = 0; j < 4; ++j) {
            f32x2 lo = __builtin_amdgcn_cvt_pk_f32_fp8(u[j], false);
            f32x2 hi = __builtin_amdgcn_cvt_pk_f32_fp8(u[j], true);
            acc[0] += lo[0]; acc[1] += lo[1]; acc[2] += hi[0]; acc[3] += hi[1];
            acc[4] += __builtin_amdgcn_cvt_f32_fp8(b[j], 0);
        }
        e += 4;
    }
    for (; e < d; ++e) {
        const unsigned char* r = m8 + (size_t)adj[s + e] * NPAD;
        unsigned int u = *(const unsigned int*)(r + cb);
        unsigned int b = r[c4];
        f32x2 lo = __builtin_amdgcn_cvt_pk_f32_fp8(u, false);
        f32x2 hi = __builtin_amdgcn_cvt_pk_f32_fp8(u, true);
        acc[0] += lo[0]; acc[1] += lo[1]; acc[2] += hi[0]; acc[3] += hi[1];
        acc[4] += __builtin_amdgcn_cvt_f32_fp8(b, 0);
    }
}

// ---------------- layer-1 aggregation: h = relu(inv_in * sum m[adj] + bias) ----------------
__global__ __launch_bounds__(256) void aggregate_fp8(const unsigned char* __restrict__ m8,
                                                     const int* __restrict__ row_start,
                                                     const int* __restrict__ deg_in,
                                                     const int* __restrict__ adj,
                                                     const float* __restrict__ inv_in,
                                                     const float* __restrict__ biasp,
                                                     bf16* __restrict__ h) {
    int node = (int)((blockIdx.x * (size_t)blockDim.x + threadIdx.x) >> 6);
    int lane = threadIdx.x & 63;
    if (node >= N_NODES) return;
    int s = row_start[node];
    int d = deg_in[node];
    float acc[5] = {};
    gather_fp8(m8, adj, s, d, lane, acc);
    float sc = inv_in[node];
    int cA = lane * 4;
    int c4 = 256 + lane;
    float4 bq = *(const float4*)(biasp + cA);
    bf16* out = h + (size_t)node * NPAD;
    __bf16 o4[4];
    o4[0] = (bf16)fmaxf(acc[0] * sc + bq.x, 0.f);
    o4[1] = (bf16)fmaxf(acc[1] * sc + bq.y, 0.f);
    o4[2] = (bf16)fmaxf(acc[2] * sc + bq.z, 0.f);
    o4[3] = (bf16)fmaxf(acc[3] * sc + bq.w, 0.f);
    *(float2*)(out + cA) = *(float2*)o4;
    out[c4] = (bf16)fmaxf(acc[4] * sc + biasp[c4], 0.f);
}

// ---------------- fused layer-2 aggregation + fc + softmax + pooling ----------------
__global__ __launch_bounds__(256) void agg2_fc_pool(const unsigned char* __restrict__ m8,
                                                    const int* __restrict__ row_start,
                                                    const int* __restrict__ deg_in,
                                                    const int* __restrict__ adj,
                                                    const float* __restrict__ inv_in,
                                                    const float* __restrict__ biasp,
                                                    const float* __restrict__ wfcp,
                                                    const float* __restrict__ bfc,
                                                    const int* __restrict__ gid,
                                                    float* __restrict__ pooled,
                                                    int* __restrict__ gcount) {
    int node = (int)((blockIdx.x * (size_t)blockDim.x + threadIdx.x) >> 6);
    int lane = threadIdx.x & 63;
    if (node >= N_NODES) return;
    int s = row_start[node];
    int d = deg_in[node];
    float acc[5] = {};
    gather_fp8(m8, adj, s, d, lane, acc);
    float sc = inv_in[node];
    int cA = lane * 4;
    int c4 = 256 + lane;
    float4 bq = *(const float4*)(biasp + cA);
    float h0 = fmaxf(acc[0] * sc + bq.x, 0.f);
    float h1 = fmaxf(acc[1] * sc + bq.y, 0.f);
    float h2 = fmaxf(acc[2] * sc + bq.z, 0.f);
    float h3 = fmaxf(acc[3] * sc + bq.w, 0.f);
    float h4 = fmaxf(acc[4] * sc + biasp[c4], 0.f);
    float4 wA0 = *(const float4*)(wfcp + cA * 2);
    float4 wA1 = *(const float4*)(wfcp + cA * 2 + 4);
    float z0 = h0 * wA0.x + h1 * wA0.z + h2 * wA1.x + h3 * wA1.z;
    float z1 = h0 * wA0.y + h1 * wA0.w + h2 * wA1.y + h3 * wA1.w;
    z0 += h4 * wfcp[c4 * 2];
    z1 += h4 * wfcp[c4 * 2 + 1];
    for (int off = 32; off; off >>= 1) {
        z0 += __shfl_down(z0, off);
        z1 += __shfl_down(z1, off);
    }
    if (lane == 0) {
        float s0 = z0 + bfc[0], s1 = z1 + bfc[1];
        float mx = fmaxf(s0, s1);
        float e0 = __expf(s0 - mx), e1 = __expf(s1 - mx);
        float inv = 1.f / (e0 + e1);
        int g = gid[node];
        atomicAdd(&pooled[g * 2 + 0], e0 * inv);
        atomicAdd(&pooled[g * 2 + 1], e1 * inv);
        atomicAdd(&gcount[g], 1);
    }
}

// ---------------- finalize: divide by counts ----------------
__global__ __launch_bounds__(256) void finalize(const float* __restrict__ pooled,
                                                const int* __restrict__ gcount,
                                                float* __restrict__ out) {
    int i = blockIdx.x * blockDim.x + threadIdx.x;
    if (i < N_GRAPHS * 2) {
        int g = i >> 1;
        float c = (float)max(gcount[g], 1);
        out[i] = pooled[i] / c;
    }
}

extern "C" void kernel_launch(void* const* d_in, const int* in_sizes, int n_in,
                              void* d_out, int out_size, void* d_ws, size_t ws_size,
                              hipStream_t stream) {
    const float* x   = (const float*)d_in[0];
    const float* W1  = (const float*)d_in[1];
    const float* b1  = (const float*)d_in[2];
    const float* W2  = (const float*)d_in[3];
    const float* b2  = (const float*)d_in[4];
    const float* Wfc = (const float*)d_in[5];
    const float* bfc = (const float*)d_in[6];
    const int* src   = (const int*)d_in[7];
    const int* dst   = (const int*)d_in[8];
    const int* gid   = (const int*)d_in[9];

    char* ws = (char*)d_ws;
    size_t off = 0;
    auto alloc = [&](size_t bytes) -> void* {
        void* p = ws + off;
        off = (off + bytes + 255) & ~(size_t)255;
        return p;
    };
    bf16* h_bf            = (bf16*)alloc((size_t)MPAD * NPAD * 2);         // 64.1 MB
    unsigned char* m8     = (unsigned char*)alloc((size_t)N_NODES * NPAD); // 32 MB
    bf16* B1t    = (bf16*)alloc((size_t)NPAD * K1PAD * 2);
    bf16* B2t    = (bf16*)alloc((size_t)NPAD * K2PAD * 2);
    int*   adj      = (int*)alloc((size_t)N_EDGES * 4);
    int*   row_st   = (int*)alloc((size_t)N_NODES * 4);
    int*   cursor   = (int*)alloc((size_t)N_NODES * 4);
    int*   deg_in   = (int*)alloc((size_t)N_NODES * 4);
    int*   deg_out  = (int*)alloc((size_t)N_NODES * 4);
    float* inv_in   = (float*)alloc((size_t)N_NODES * 4);
    float* inv_out  = (float*)alloc((size_t)N_NODES * 4);
    const int NB = (N_NODES + 255) / 256;
    int*   bsum     = (int*)alloc((size_t)NB * 4);
    int*   boff     = (int*)alloc((size_t)NB * 4);
    float* pooled   = (float*)alloc((size_t)N_GRAPHS * 2 * 4);
    int*   gcount   = (int*)alloc((size_t)N_GRAPHS * 4);
    float* b1p      = (float*)alloc((size_t)NPAD * 4);
    float* b2p      = (float*)alloc((size_t)NPAD * 4);
    float* wfcp     = (float*)alloc((size_t)NPAD * 2 * 4);

    hipMemsetAsync(deg_in, 0, (size_t)N_NODES * 4, stream);
    hipMemsetAsync(deg_out, 0, (size_t)N_NODES * 4, stream);
    hipMemsetAsync(pooled, 0, (size_t)N_GRAPHS * 2 * 4, stream);
    hipMemsetAsync(gcount, 0, (size_t)N_GRAPHS * 4, stream);

    // graph preprocessing
    count_deg<<<(N_EDGES + 255) / 256, 256, 0, stream>>>(src, dst, deg_out, deg_in);
    block_sum<<<NB, 256, 0, stream>>>(deg_in, bsum);
    scan_serial<<<1, 64, 0, stream>>>(bsum, boff, NB);
    node_offsets<<<NB, 256, 0, stream>>>(deg_in, deg_out, boff, row_st, cursor, inv_in, inv_out);
    fill_csr<<<(N_EDGES + 255) / 256, 256, 0, stream>>>(src, dst, cursor, adj);

    // weight conversions + padded small tensors
    conv_bt<<<(NPAD * K1PAD + 255) / 256, 256, 0, stream>>>(W1, B1t, D_IN, D_H, K1PAD);
    conv_bt<<<(NPAD * K2PAD + 255) / 256, 256, 0, stream>>>(W2, B2t, D_H, D_H, K2PAD);
    prep_small<<<3, 256, 0, stream>>>(b1, b2, Wfc, b1p, b2p, wfcp);

    dim3 ggrid(MPAD / 128, 2);   // 782 x 2 column-halves

    // layer 1 (reg-staged fp32 A, fp8 m output)
    gemm_rs<10, true><<<ggrid, 256, 0, stream>>>(x, nullptr, B1t, inv_out, m8, N_NODES);
    aggregate_fp8<<<(N_NODES * 64 + 255) / 256, 256, 0, stream>>>(m8, row_st, deg_in, adj, inv_in, b1p, h_bf);
    // layer 2 (reg-staged bf16 A)
    gemm_rs<5, false><<<ggrid, 256, 0, stream>>>(nullptr, h_bf, B2t, inv_out, m8, N_NODES);
    // fused layer-2 aggregate + fc + softmax + pooling
    agg2_fc_pool<<<(N_NODES * 64 + 255) / 256, 256, 0, stream>>>(m8, row_st, deg_in, adj, inv_in, b2p,
                                                                 wfcp, bfc, gid, pooled, gcount);
    finalize<<<(N_GRAPHS * 2 + 255) / 256, 256, 0, stream>>>(pooled, gcount, (float*)d_out);
}